// Round 3
// baseline (93.249 us; speedup 1.0000x reference)
//
#include <hip/hip_runtime.h>
#include <hip/hip_bf16.h>

typedef __bf16 bf16x8 __attribute__((ext_vector_type(8)));
typedef __bf16 bf16x4 __attribute__((ext_vector_type(4)));
typedef float  f32x4  __attribute__((ext_vector_type(4)));

constexpr int Bn = 8192, Dn = 64, On = 256;

// ---- prep: betasT bf16 [O][e][d] (A-operand layout) + NEGATED c_proj fp32 ----
__global__ void k_prep_beta(const float* __restrict__ betas, const float* __restrict__ centers,
                            __bf16* __restrict__ bT, float* __restrict__ ncproj) {
    __shared__ float s[64 * 65];                        // +1 pad: conflict-free transpose
    const int o = blockIdx.x, tid = threadIdx.x;
    const float* bo = betas + (size_t)o * 4096;         // betas[o][d][e]
    for (int j = tid; j < 1024; j += 256) {             // float4 quads over [d][e]
        int d = j >> 4, e = (j & 15) * 4;
        float4 v = ((const float4*)bo)[j];
        s[d * 65 + e + 0] = v.x; s[d * 65 + e + 1] = v.y;
        s[d * 65 + e + 2] = v.z; s[d * 65 + e + 3] = v.w;
    }
    __syncthreads();
    for (int j = tid; j < 1024; j += 256) {             // quads over [e][d]
        int e = j >> 4, d = (j & 15) * 4;
        bf16x4 r;
        r[0] = (__bf16)s[(d + 0) * 65 + e]; r[1] = (__bf16)s[(d + 1) * 65 + e];
        r[2] = (__bf16)s[(d + 2) * 65 + e]; r[3] = (__bf16)s[(d + 3) * 65 + e];
        *(bf16x4*)(bT + (size_t)o * 4096 + e * 64 + d) = r;
    }
    if (tid < 64) {
        float acc = 0.f;
        for (int d = 0; d < 64; ++d) acc += s[d * 65 + tid] * centers[o * 64 + d];
        ncproj[o * 64 + tid] = -acc;                    // negated: MFMA C-init
    }
}

// ---- main: block = 4 waves, 4 o's (1/wave), 256 b. x staged bf16 in LDS
//      (144 B rows). acc init = -cproj -> acc = y - cp; q = sum acc^2.
//      Per-lane e-quarter partials in regs; one LDS transpose at end. ----
__global__ __launch_bounds__(256, 4) void k_main(const float* __restrict__ x,
                                                 const __bf16* __restrict__ bT,
                                                 const float* __restrict__ ncproj,
                                                 float* __restrict__ out) {
    __shared__ __align__(16) unsigned char smem[256 * 144];   // 36 KB -> 4 blocks/CU
    __bf16* sX = (__bf16*)smem;                         // [256 rows][72 elems] (pad 8)
    float*  sQ = (float*)smem;                          // alias: [256 b][20] after barrier

    const int tid  = threadIdx.x;
    const int w    = tid >> 6, lane = tid & 63;
    const int col  = lane & 15, grp = lane >> 4;
    const int bbase = blockIdx.x * 256;                 // b fast dim -> o-blocks share XCD
    const int o     = blockIdx.y * 4 + w;

    // A-fragments (betaT) + neg-cproj, register-resident for this wave's o
    const __bf16* bo = bT + (size_t)o * 4096 + (size_t)col * 64 + grp * 8;
    const float*  cp = ncproj + o * 64 + grp * 4;
    bf16x8 A[4][2];
    f32x4  ncp[4];
#pragma unroll
    for (int mi = 0; mi < 4; ++mi) {
        A[mi][0] = *(const bf16x8*)(bo + mi * 16 * 64);
        A[mi][1] = *(const bf16x8*)(bo + mi * 16 * 64 + 32);
        ncp[mi]  = *(const f32x4*)(cp + mi * 16);       // e = mi*16 + grp*4 + r
    }

    // stage x fp32 -> bf16 LDS (fused convert), coalesced float4 reads
#pragma unroll
    for (int it = 0; it < 16; ++it) {
        int i = it * 256 + tid;                         // 256 rows x 16 quads
        int row = i >> 4, q4 = i & 15;
        float4 v = ((const float4*)(x + (size_t)(bbase + row) * 64))[q4];
        bf16x4 r;
        r[0] = (__bf16)v.x; r[1] = (__bf16)v.y; r[2] = (__bf16)v.z; r[3] = (__bf16)v.w;
        *(bf16x4*)(sX + row * 72 + q4 * 4) = r;
    }
    __syncthreads();

    float qp[16];                                       // per-n e-quarter partial
#pragma unroll
    for (int n = 0; n < 16; ++n) {
        const __bf16* xr = sX + (n * 16 + col) * 72 + grp * 8;
        bf16x8 x0 = *(const bf16x8*)(xr);               // d = grp*8 .. +7
        bf16x8 x1 = *(const bf16x8*)(xr + 32);          // d = 32 + grp*8 .. +7
        f32x4 qv = {0.f, 0.f, 0.f, 0.f};
#pragma unroll
        for (int mi = 0; mi < 4; ++mi) {
            f32x4 acc = ncp[mi];                        // C-init = -cp -> acc = y - cp
            acc = __builtin_amdgcn_mfma_f32_16x16x32_bf16(A[mi][0], x0, acc, 0, 0, 0);
            acc = __builtin_amdgcn_mfma_f32_16x16x32_bf16(A[mi][1], x1, acc, 0, 0, 0);
            qv += acc * acc;                            // packed-fp32
        }
        qp[n] = (qv[0] + qv[1]) + (qv[2] + qv[3]);      // lane's 16-e partial for b=n*16+col
    }
    __syncthreads();                                    // all waves done reading sX

    // transpose via LDS (aliased): sQ[b_local][w*4 + grp], row stride 20 floats (80 B)
#pragma unroll
    for (int n = 0; n < 16; ++n)
        sQ[(n * 16 + col) * 20 + w * 4 + grp] = qp[n];
    __syncthreads();

    // thread tid = local b: sum grp-quarters per o, exp, one coalesced 16 B store
    const float* qr = sQ + tid * 20;
    f32x4 r;
#pragma unroll
    for (int j = 0; j < 4; ++j) {                       // j = wave index = o offset
        f32x4 v = *(const f32x4*)(qr + j * 4);
        r[j] = __expf(-((v[0] + v[1]) + (v[2] + v[3])));
    }
    *(f32x4*)(out + (size_t)(bbase + tid) * 256 + blockIdx.y * 4) = r;
}

extern "C" void kernel_launch(void* const* d_in, const int* in_sizes, int n_in,
                              void* d_out, int out_size, void* d_ws, size_t ws_size,
                              hipStream_t stream) {
    const float* x       = (const float*)d_in[0];   // [8192,64]
    const float* centers = (const float*)d_in[1];   // [256,1,64]
    const float* betas   = (const float*)d_in[2];   // [256,64,64]
    float* out = (float*)d_out;                     // [8192,256] fp32

    char* ws = (char*)d_ws;
    __bf16* bT   = (__bf16*)ws;                     // 2 MB
    float*  ncpj = (float*)(ws + 2 * (1 << 20));    // 64 KB

    k_prep_beta<<<dim3(On),               dim3(256), 0, stream>>>(betas, centers, bT, ncpj);
    k_main     <<<dim3(Bn / 256, On / 4), dim3(256), 0, stream>>>(x, bT, ncpj, out);
}